// Round 1
// baseline (1535.768 us; speedup 1.0000x reference)
//
#include <hip/hip_runtime.h>
#include <math.h>

// WormNetCalcium: N=300 neurons, WIN=1024 raw frames upsampled x16 -> T=16384.
// Outputs (flat, in return order), each N*T fp32:
//  0 mu_v_prob | 1 mu_fluorescence | 2 mu_lat | 3 lv_lat | 4 sample
//  5 calcium_activation | 6 mu_calcium_prob | 7 recurrent_in | 8 sensory_input
//
// Structure:
//  k_sensory: sensory_input = mask[n] * (odor @ W_enc^T + b_enc)^T
//  k_latent : mu_lat/lv_lat = A@f_up + B@S (4 GEMMs fused), sample = mu+exp(.5lv)*eps
//  k_recur  : recurrent_in = Wc@relu(sample)+We@sample, + mu_v_prob + calcium_act
//  k_scan   : per-neuron linear recurrence c[t]=decay*c[t-1]+x[t], c[0]=init+x[0]
//             (block per neuron, 256 chunks of 64, affine-carry combine)

#define NN   300
#define WINSZ 1024
#define TT   16384
#define ODORD 16
#define DTC  0.2f
#define NTOT (NN * TT)
#define NT1  15   // rows per thread in GEMM kernels (300 = 20 * 15)

__global__ __launch_bounds__(256) void k_sensory(
    const float* __restrict__ odor, const float* __restrict__ Wenc,
    const float* __restrict__ benc, const float* __restrict__ mask,
    float* __restrict__ S)
{
    int t = blockIdx.x * 256 + threadIdx.x;
    float o[16];
    const float4* op = reinterpret_cast<const float4*>(odor + (size_t)t * ODORD);
    #pragma unroll
    for (int i = 0; i < 4; ++i) {
        float4 v = op[i];
        o[4*i+0] = v.x; o[4*i+1] = v.y; o[4*i+2] = v.z; o[4*i+3] = v.w;
    }
    for (int n = 0; n < NN; ++n) {
        float enc = benc[n];
        #pragma unroll
        for (int k = 0; k < ODORD; ++k)
            enc = fmaf(o[k], Wenc[n*ODORD + k], enc);
        S[(size_t)n*TT + t] = enc * mask[n];
    }
}

__global__ __launch_bounds__(256) void k_latent(
    const float* __restrict__ Amu, const float* __restrict__ Bmu,
    const float* __restrict__ Alv, const float* __restrict__ Blv,
    const float* __restrict__ raw, const float* __restrict__ S,
    const float* __restrict__ eps,
    float* __restrict__ mu_lat, float* __restrict__ lv_lat,
    float* __restrict__ sample)
{
    int t  = blockIdx.x * 256 + threadIdx.x;
    int n0 = blockIdx.y * NT1;
    int tw = t >> 4;  // upsample-by-16 source column
    float amu[NT1], alv[NT1];
    #pragma unroll
    for (int i = 0; i < NT1; ++i) { amu[i] = 0.f; alv[i] = 0.f; }
    for (int k = 0; k < NN; ++k) {
        float fu = raw[k*WINSZ + tw];
        float s  = S[(size_t)k*TT + t];
        #pragma unroll
        for (int i = 0; i < NT1; ++i) {
            amu[i] = fmaf(Amu[(n0+i)*NN + k], fu, amu[i]);
            amu[i] = fmaf(Bmu[(n0+i)*NN + k], s,  amu[i]);
            alv[i] = fmaf(Alv[(n0+i)*NN + k], fu, alv[i]);
            alv[i] = fmaf(Blv[(n0+i)*NN + k], s,  alv[i]);
        }
    }
    #pragma unroll
    for (int i = 0; i < NT1; ++i) {
        size_t idx = (size_t)(n0+i)*TT + t;
        float mu = amu[i], lv = alv[i];
        mu_lat[idx] = mu;
        lv_lat[idx] = lv;
        sample[idx] = fmaf(expf(0.5f*lv), eps[idx], mu);
    }
}

__global__ __launch_bounds__(256) void k_recur(
    const float* __restrict__ Wc, const float* __restrict__ We,
    const float* __restrict__ sample, const float* __restrict__ S,
    const float* __restrict__ bias, const float* __restrict__ tau,
    const float* __restrict__ aw, const float* __restrict__ ab,
    float* __restrict__ rec, float* __restrict__ muv, float* __restrict__ cact)
{
    int t  = blockIdx.x * 256 + threadIdx.x;
    int n0 = blockIdx.y * NT1;
    float acc[NT1];
    #pragma unroll
    for (int i = 0; i < NT1; ++i) acc[i] = 0.f;
    for (int k = 0; k < NN; ++k) {
        float s  = sample[(size_t)k*TT + t];
        float rs = fmaxf(s, 0.f);
        #pragma unroll
        for (int i = 0; i < NT1; ++i) {
            acc[i] = fmaf(Wc[(n0+i)*NN + k], rs, acc[i]);
            acc[i] = fmaf(We[(n0+i)*NN + k], s,  acc[i]);
        }
    }
    #pragma unroll
    for (int i = 0; i < NT1; ++i) {
        int n = n0 + i;
        size_t idx = (size_t)n*TT + t;
        float r  = acc[i];
        float s  = sample[idx];
        float sv = S[idx];
        float av = DTC / fmaxf(tau[n], DTC);
        rec[idx] = r;
        muv[idx] = s + av * (-s + r + sv + bias[n]);
        float xx = fmaf(aw[n], s, ab[n]);
        // stable softplus == jax.nn.softplus
        cact[idx] = fmaxf(xx, 0.f) + log1pf(expf(-fabsf(xx)));
    }
}

// One block per neuron. 256 threads, each owns a contiguous chunk of 64.
// Pass1: per-chunk value S_j (chunk 0 includes init with NO decay on the
// first step, matching c[0]=init+x[0]). Thread 0 serially composes affine
// carries: carry_1 = S_0; carry_j = d64*carry_{j-1} + S_{j-1}. Pass2 replays.
__global__ __launch_bounds__(256) void k_scan(
    const float* __restrict__ cact, const float* __restrict__ ffull,
    const float* __restrict__ ctau, const float* __restrict__ fscale,
    const float* __restrict__ fshift,
    float* __restrict__ mu_fl, float* __restrict__ mu_cal)
{
    __shared__ float Slds[256];
    __shared__ float Clds[256];
    int n   = blockIdx.x;
    int tid = threadIdx.x;
    float alpha = DTC / fmaxf(ctau[n], DTC);
    float decay = expf(-alpha);
    float d64   = expf(-64.f * alpha);
    float scale = fscale[n], shift = fshift[n];
    float init  = (ffull[(size_t)n*TT] - shift) / scale;

    const float4* x4 = reinterpret_cast<const float4*>(cact + (size_t)n*TT + tid*64);

    // pass 1: chunk suffix value
    float4 v = x4[0];
    float acc = (tid == 0) ? (init + v.x) : v.x;
    acc = fmaf(decay, acc, v.y);
    acc = fmaf(decay, acc, v.z);
    acc = fmaf(decay, acc, v.w);
    for (int i = 1; i < 16; ++i) {
        v = x4[i];
        acc = fmaf(decay, acc, v.x);
        acc = fmaf(decay, acc, v.y);
        acc = fmaf(decay, acc, v.z);
        acc = fmaf(decay, acc, v.w);
    }
    Slds[tid] = acc;
    __syncthreads();

    if (tid == 0) {
        Clds[0] = 0.f;            // unused
        float running = Slds[0];  // carry_1
        Clds[1] = running;
        for (int j = 2; j < 256; ++j) {
            running = fmaf(d64, running, Slds[j-1]);
            Clds[j] = running;
        }
    }
    __syncthreads();
    float carry = Clds[tid];

    // pass 2: replay with carry, write c and fl_scale*c+fl_shift
    float4* ocal = reinterpret_cast<float4*>(mu_cal + (size_t)n*TT + tid*64);
    float4* ofl  = reinterpret_cast<float4*>(mu_fl  + (size_t)n*TT + tid*64);

    float4 vv = x4[0];
    float c;
    if (tid == 0) c = init + vv.x;
    else          c = fmaf(decay, carry, vv.x);
    float4 oc, of;
    oc.x = c; of.x = fmaf(scale, c, shift);
    c = fmaf(decay, c, vv.y); oc.y = c; of.y = fmaf(scale, c, shift);
    c = fmaf(decay, c, vv.z); oc.z = c; of.z = fmaf(scale, c, shift);
    c = fmaf(decay, c, vv.w); oc.w = c; of.w = fmaf(scale, c, shift);
    ocal[0] = oc; ofl[0] = of;
    for (int i = 1; i < 16; ++i) {
        vv = x4[i];
        c = fmaf(decay, c, vv.x); oc.x = c; of.x = fmaf(scale, c, shift);
        c = fmaf(decay, c, vv.y); oc.y = c; of.y = fmaf(scale, c, shift);
        c = fmaf(decay, c, vv.z); oc.z = c; of.z = fmaf(scale, c, shift);
        c = fmaf(decay, c, vv.w); oc.w = c; of.w = fmaf(scale, c, shift);
        ocal[i] = oc; ofl[i] = of;
    }
}

extern "C" void kernel_launch(void* const* d_in, const int* in_sizes, int n_in,
                              void* d_out, int out_size, void* d_ws, size_t ws_size,
                              hipStream_t stream) {
    const float* raw   = (const float*)d_in[0];   // fluorescence_raw_target (N,WIN)
    const float* ffull = (const float*)d_in[1];   // fluorescence_full_target (N,T)
    const float* odor  = (const float*)d_in[2];   // (T,16)
    const float* mask  = (const float*)d_in[3];   // (N)
    const float* Wenc  = (const float*)d_in[4];   // (N,16)
    const float* benc  = (const float*)d_in[5];   // (N)
    const float* Amu   = (const float*)d_in[6];   // (N,N)
    const float* Bmu   = (const float*)d_in[7];
    const float* Alv   = (const float*)d_in[8];
    const float* Blv   = (const float*)d_in[9];
    const float* eps   = (const float*)d_in[10];  // (N,T)
    const float* Wc    = (const float*)d_in[11];
    const float* We    = (const float*)d_in[12];
    const float* nbias = (const float*)d_in[13];
    const float* ntau  = (const float*)d_in[14];
    const float* aw    = (const float*)d_in[15];
    const float* ab    = (const float*)d_in[16];
    const float* fsc   = (const float*)d_in[17];
    const float* fsh   = (const float*)d_in[18];
    const float* ctau  = (const float*)d_in[19];

    float* out    = (float*)d_out;
    float* o_muv  = out + 0*(size_t)NTOT;
    float* o_mufl = out + 1*(size_t)NTOT;
    float* o_mul  = out + 2*(size_t)NTOT;
    float* o_lvl  = out + 3*(size_t)NTOT;
    float* o_samp = out + 4*(size_t)NTOT;
    float* o_cact = out + 5*(size_t)NTOT;
    float* o_mcal = out + 6*(size_t)NTOT;
    float* o_rec  = out + 7*(size_t)NTOT;
    float* o_sens = out + 8*(size_t)NTOT;

    hipLaunchKernelGGL(k_sensory, dim3(TT/256), dim3(256), 0, stream,
                       odor, Wenc, benc, mask, o_sens);
    hipLaunchKernelGGL(k_latent, dim3(TT/256, NN/NT1), dim3(256), 0, stream,
                       Amu, Bmu, Alv, Blv, raw, o_sens, eps, o_mul, o_lvl, o_samp);
    hipLaunchKernelGGL(k_recur, dim3(TT/256, NN/NT1), dim3(256), 0, stream,
                       Wc, We, o_samp, o_sens, nbias, ntau, aw, ab,
                       o_rec, o_muv, o_cact);
    hipLaunchKernelGGL(k_scan, dim3(NN), dim3(256), 0, stream,
                       o_cact, ffull, ctau, fsc, fsh, o_mufl, o_mcal);
}

// Round 2
// 580.545 us; speedup vs baseline: 2.6454x; 2.6454x over previous
//
#include <hip/hip_runtime.h>
#include <math.h>

// WormNetCalcium on MFMA. N=300, WIN=1024, R=16, T=16384.
// K layout (padded to 640): [0..299]=f_up/A-part, [300..303]=0,
//                           [304..603]=S/B-part,  [604..639]=0.
// Wlat rows interleaved: row 2i = [A_mu[i]|B_mu[i]], row 2i+1 = [A_lv[i]|B_lv[i]]
// so a D-fragment's 4 consecutive rows hold (mu,lv) pairs for 2 neurons.
// Pipeline: k_prepW, k_stage1 (X1^T bf16 + sensory), k_gemm1 (mu/lv/sample +
// X2^T bf16), k_gemm2 (rec/muv/cact), k_scan (calcium recurrence).

#define NN    300
#define WINSZ 1024
#define TT    16384
#define KP    640
#define DTC   0.2f
#define NTOT  (NN * TT)

typedef short  short8 __attribute__((ext_vector_type(8)));
typedef float  f32x4  __attribute__((ext_vector_type(4)));

__device__ inline short bf16rne(float f) {
    unsigned u = __float_as_uint(f);
    u += 0x7fffu + ((u >> 16) & 1u);
    return (short)(u >> 16);
}

// ---------------- weight prep: fp32 -> bf16, fused+interleaved+padded -------
__global__ __launch_bounds__(256) void k_prepW(
    const float* __restrict__ Amu, const float* __restrict__ Bmu,
    const float* __restrict__ Alv, const float* __restrict__ Blv,
    const float* __restrict__ Wc,  const float* __restrict__ We,
    short* __restrict__ Wlat, short* __restrict__ Wrec)
{
    int row = blockIdx.x;
    int tid = threadIdx.x;
    if (row < 640) {
        int i = row >> 1, lv = row & 1;
        const float* A = lv ? Alv : Amu;
        const float* B = lv ? Blv : Bmu;
        for (int k = tid; k < KP; k += 256) {
            float v = 0.f;
            if (row < 600) {
                if (k < 300)                 v = A[i*300 + k];
                else if (k >= 304 && k < 604) v = B[i*300 + (k-304)];
            }
            Wlat[(size_t)row*KP + k] = bf16rne(v);
        }
    } else {
        int m = row - 640;   // 0..383
        for (int k = tid; k < KP; k += 256) {
            float v = 0.f;
            if (m < 300) {
                if (k < 300)                 v = Wc[m*300 + k];
                else if (k >= 304 && k < 604) v = We[m*300 + (k-304)];
            }
            Wrec[(size_t)m*KP + k] = bf16rne(v);
        }
    }
}

// ---------------- stage1: X1^T bf16 (f_up | S), sensory_input fp32 ----------
__global__ __launch_bounds__(256) void k_stage1(
    const float* __restrict__ odor, const float* __restrict__ Wenc,
    const float* __restrict__ benc, const float* __restrict__ mask,
    const float* __restrict__ raw,
    float* __restrict__ S, short* __restrict__ Xt1, short* __restrict__ Xt2)
{
    int t = blockIdx.x * 256 + threadIdx.x;
    float o[16];
    const float4* op = reinterpret_cast<const float4*>(odor + (size_t)t * 16);
    #pragma unroll
    for (int i = 0; i < 4; ++i) {
        float4 v = op[i];
        o[4*i+0] = v.x; o[4*i+1] = v.y; o[4*i+2] = v.z; o[4*i+3] = v.w;
    }
    int tw = t >> 4;
    short* xrow = Xt1 + (size_t)t * KP;
    // f_up section [0,304)
    for (int n0 = 0; n0 < 304; n0 += 8) {
        short8 v;
        #pragma unroll
        for (int j = 0; j < 8; ++j) {
            int n = n0 + j;
            float rv = (n < NN) ? raw[n*WINSZ + tw] : 0.f;
            v[j] = bf16rne(rv);
        }
        *(short8*)(xrow + n0) = v;
    }
    // S section [304,608)
    for (int n0 = 0; n0 < 304; n0 += 8) {
        short8 v;
        #pragma unroll
        for (int j = 0; j < 8; ++j) {
            int n = n0 + j;
            float s = 0.f;
            if (n < NN) {
                float enc = benc[n];
                #pragma unroll
                for (int k = 0; k < 16; ++k)
                    enc = fmaf(o[k], Wenc[n*16 + k], enc);
                s = enc * mask[n];
                S[(size_t)n*TT + t] = s;
            }
            v[j] = bf16rne(s);
        }
        *(short8*)(xrow + 304 + n0) = v;
    }
    // tail zeros [608,640)
    short8 z = {0,0,0,0,0,0,0,0};
    for (int n0 = 608; n0 < 640; n0 += 8) *(short8*)(xrow + n0) = z;
    // Xt2 pad zeros: [300,304), [604,608), [608,640)
    short* x2 = Xt2 + (size_t)t * KP;
    *(long long*)(x2 + 300) = 0ll;
    *(long long*)(x2 + 604) = 0ll;
    for (int n0 = 608; n0 < 640; n0 += 8) *(short8*)(x2 + n0) = z;
}

// ---------------- GEMM1: C(640x16384) = Wlat @ X1, epilogue mu/lv/sample ----
__global__ __launch_bounds__(256) void k_gemm1(
    const short* __restrict__ Wlat, const short* __restrict__ Xt1,
    const float* __restrict__ eps,
    float* __restrict__ mu_lat, float* __restrict__ lv_lat,
    float* __restrict__ sample, short* __restrict__ Xt2)
{
    __shared__ short Asm[128*32];
    __shared__ short Bsm[128*32];
    int tid  = threadIdx.x;
    int lane = tid & 63, w = tid >> 6;
    int wr = w >> 1, wc = w & 1;
    int n0 = blockIdx.x * 128;           // t tile
    int m0 = blockIdx.y * 128;           // row tile
    f32x4 acc[4][4];
    #pragma unroll
    for (int a = 0; a < 4; ++a)
        #pragma unroll
        for (int b = 0; b < 4; ++b) acc[a][b] = (f32x4)(0.f);

    for (int k0 = 0; k0 < KP; k0 += 32) {
        __syncthreads();
        {
            int c0 = tid, c1 = tid + 256;
            *(((int4*)Asm) + c0) = *(const int4*)(Wlat + (size_t)(m0 + (c0>>2))*KP + k0 + (c0&3)*8);
            *(((int4*)Asm) + c1) = *(const int4*)(Wlat + (size_t)(m0 + (c1>>2))*KP + k0 + (c1&3)*8);
            *(((int4*)Bsm) + c0) = *(const int4*)(Xt1 + (size_t)(n0 + (c0>>2))*KP + k0 + (c0&3)*8);
            *(((int4*)Bsm) + c1) = *(const int4*)(Xt1 + (size_t)(n0 + (c1>>2))*KP + k0 + (c1&3)*8);
        }
        __syncthreads();
        short8 a[4], b[4];
        #pragma unroll
        for (int mi = 0; mi < 4; ++mi)
            a[mi] = *(const short8*)(Asm + (wr*64 + mi*16 + (lane&15))*32 + ((lane>>4)<<3));
        #pragma unroll
        for (int ni = 0; ni < 4; ++ni)
            b[ni] = *(const short8*)(Bsm + (wc*64 + ni*16 + (lane&15))*32 + ((lane>>4)<<3));
        #pragma unroll
        for (int mi = 0; mi < 4; ++mi)
            #pragma unroll
            for (int ni = 0; ni < 4; ++ni)
                acc[mi][ni] = __builtin_amdgcn_mfma_f32_16x16x32_bf16(a[mi], b[ni], acc[mi][ni], 0, 0, 0);
    }

    #pragma unroll
    for (int mi = 0; mi < 4; ++mi) {
        int gmB = m0 + wr*64 + mi*16 + ((lane>>4)<<2);  // even
        if (gmB >= 600) continue;
        int i0 = gmB >> 1;
        #pragma unroll
        for (int ni = 0; ni < 4; ++ni) {
            int gt = n0 + wc*64 + ni*16 + (lane&15);
            f32x4 v = acc[mi][ni];
            {
                size_t idx = (size_t)i0*TT + gt;
                float mu = v[0], lv = v[1];
                mu_lat[idx] = mu; lv_lat[idx] = lv;
                float s = fmaf(expf(0.5f*lv), eps[idx], mu);
                sample[idx] = s;
                Xt2[(size_t)gt*KP + i0]       = bf16rne(fmaxf(s, 0.f));
                Xt2[(size_t)gt*KP + 304 + i0] = bf16rne(s);
            }
            if (i0 + 1 < NN) {
                size_t idx = (size_t)(i0+1)*TT + gt;
                float mu = v[2], lv = v[3];
                mu_lat[idx] = mu; lv_lat[idx] = lv;
                float s = fmaf(expf(0.5f*lv), eps[idx], mu);
                sample[idx] = s;
                Xt2[(size_t)gt*KP + i0 + 1]       = bf16rne(fmaxf(s, 0.f));
                Xt2[(size_t)gt*KP + 304 + i0 + 1] = bf16rne(s);
            }
        }
    }
}

// ---------------- GEMM2: rec = Wrec @ X2, epilogue muv/cact ----------------
__global__ __launch_bounds__(256) void k_gemm2(
    const short* __restrict__ Wrec, const short* __restrict__ Xt2,
    const float* __restrict__ sample, const float* __restrict__ S,
    const float* __restrict__ bias, const float* __restrict__ tau,
    const float* __restrict__ aw, const float* __restrict__ ab,
    float* __restrict__ rec, float* __restrict__ muv, float* __restrict__ cact)
{
    __shared__ short Asm[128*32];
    __shared__ short Bsm[128*32];
    int tid  = threadIdx.x;
    int lane = tid & 63, w = tid >> 6;
    int wr = w >> 1, wc = w & 1;
    int n0 = blockIdx.x * 128;
    int m0 = blockIdx.y * 128;
    f32x4 acc[4][4];
    #pragma unroll
    for (int a = 0; a < 4; ++a)
        #pragma unroll
        for (int b = 0; b < 4; ++b) acc[a][b] = (f32x4)(0.f);

    for (int k0 = 0; k0 < KP; k0 += 32) {
        __syncthreads();
        {
            int c0 = tid, c1 = tid + 256;
            *(((int4*)Asm) + c0) = *(const int4*)(Wrec + (size_t)(m0 + (c0>>2))*KP + k0 + (c0&3)*8);
            *(((int4*)Asm) + c1) = *(const int4*)(Wrec + (size_t)(m0 + (c1>>2))*KP + k0 + (c1&3)*8);
            *(((int4*)Bsm) + c0) = *(const int4*)(Xt2 + (size_t)(n0 + (c0>>2))*KP + k0 + (c0&3)*8);
            *(((int4*)Bsm) + c1) = *(const int4*)(Xt2 + (size_t)(n0 + (c1>>2))*KP + k0 + (c1&3)*8);
        }
        __syncthreads();
        short8 a[4], b[4];
        #pragma unroll
        for (int mi = 0; mi < 4; ++mi)
            a[mi] = *(const short8*)(Asm + (wr*64 + mi*16 + (lane&15))*32 + ((lane>>4)<<3));
        #pragma unroll
        for (int ni = 0; ni < 4; ++ni)
            b[ni] = *(const short8*)(Bsm + (wc*64 + ni*16 + (lane&15))*32 + ((lane>>4)<<3));
        #pragma unroll
        for (int mi = 0; mi < 4; ++mi)
            #pragma unroll
            for (int ni = 0; ni < 4; ++ni)
                acc[mi][ni] = __builtin_amdgcn_mfma_f32_16x16x32_bf16(a[mi], b[ni], acc[mi][ni], 0, 0, 0);
    }

    #pragma unroll
    for (int mi = 0; mi < 4; ++mi) {
        int gmB = m0 + wr*64 + mi*16 + ((lane>>4)<<2);
        if (gmB >= NN) continue;
        #pragma unroll
        for (int ni = 0; ni < 4; ++ni) {
            int gt = n0 + wc*64 + ni*16 + (lane&15);
            f32x4 v = acc[mi][ni];
            #pragma unroll
            for (int r = 0; r < 4; ++r) {
                int n = gmB + r;
                if (n < NN) {
                    size_t idx = (size_t)n*TT + gt;
                    float rv = v[r];
                    float s  = sample[idx];
                    float sv = S[idx];
                    float av = DTC / fmaxf(tau[n], DTC);
                    rec[idx] = rv;
                    muv[idx] = s + av * (-s + rv + sv + bias[n]);
                    float xx = fmaf(aw[n], s, ab[n]);
                    cact[idx] = fmaxf(xx, 0.f) + log1pf(expf(-fabsf(xx)));
                }
            }
        }
    }
}

// ---------------- scan: c[t]=decay*c[t-1]+x[t], c[0]=init+x[0] -------------
__global__ __launch_bounds__(256) void k_scan(
    const float* __restrict__ cact, const float* __restrict__ ffull,
    const float* __restrict__ ctau, const float* __restrict__ fscale,
    const float* __restrict__ fshift,
    float* __restrict__ mu_fl, float* __restrict__ mu_cal)
{
    __shared__ float Slds[256];
    __shared__ float Clds[256];
    int n   = blockIdx.x;
    int tid = threadIdx.x;
    float alpha = DTC / fmaxf(ctau[n], DTC);
    float decay = expf(-alpha);
    float d64   = expf(-64.f * alpha);
    float scale = fscale[n], shift = fshift[n];
    float init  = (ffull[(size_t)n*TT] - shift) / scale;

    const float4* x4 = reinterpret_cast<const float4*>(cact + (size_t)n*TT + tid*64);

    float4 v = x4[0];
    float acc = (tid == 0) ? (init + v.x) : v.x;
    acc = fmaf(decay, acc, v.y);
    acc = fmaf(decay, acc, v.z);
    acc = fmaf(decay, acc, v.w);
    for (int i = 1; i < 16; ++i) {
        v = x4[i];
        acc = fmaf(decay, acc, v.x);
        acc = fmaf(decay, acc, v.y);
        acc = fmaf(decay, acc, v.z);
        acc = fmaf(decay, acc, v.w);
    }
    Slds[tid] = acc;
    __syncthreads();

    if (tid == 0) {
        Clds[0] = 0.f;
        float running = Slds[0];
        Clds[1] = running;
        for (int j = 2; j < 256; ++j) {
            running = fmaf(d64, running, Slds[j-1]);
            Clds[j] = running;
        }
    }
    __syncthreads();
    float carry = Clds[tid];

    float4* ocal = reinterpret_cast<float4*>(mu_cal + (size_t)n*TT + tid*64);
    float4* ofl  = reinterpret_cast<float4*>(mu_fl  + (size_t)n*TT + tid*64);

    float4 vv = x4[0];
    float c;
    if (tid == 0) c = init + vv.x;
    else          c = fmaf(decay, carry, vv.x);
    float4 oc, of;
    oc.x = c; of.x = fmaf(scale, c, shift);
    c = fmaf(decay, c, vv.y); oc.y = c; of.y = fmaf(scale, c, shift);
    c = fmaf(decay, c, vv.z); oc.z = c; of.z = fmaf(scale, c, shift);
    c = fmaf(decay, c, vv.w); oc.w = c; of.w = fmaf(scale, c, shift);
    ocal[0] = oc; ofl[0] = of;
    for (int i = 1; i < 16; ++i) {
        vv = x4[i];
        c = fmaf(decay, c, vv.x); oc.x = c; of.x = fmaf(scale, c, shift);
        c = fmaf(decay, c, vv.y); oc.y = c; of.y = fmaf(scale, c, shift);
        c = fmaf(decay, c, vv.z); oc.z = c; of.z = fmaf(scale, c, shift);
        c = fmaf(decay, c, vv.w); oc.w = c; of.w = fmaf(scale, c, shift);
        ocal[i] = oc; ofl[i] = of;
    }
}

extern "C" void kernel_launch(void* const* d_in, const int* in_sizes, int n_in,
                              void* d_out, int out_size, void* d_ws, size_t ws_size,
                              hipStream_t stream) {
    const float* raw   = (const float*)d_in[0];
    const float* ffull = (const float*)d_in[1];
    const float* odor  = (const float*)d_in[2];
    const float* mask  = (const float*)d_in[3];
    const float* Wenc  = (const float*)d_in[4];
    const float* benc  = (const float*)d_in[5];
    const float* Amu   = (const float*)d_in[6];
    const float* Bmu   = (const float*)d_in[7];
    const float* Alv   = (const float*)d_in[8];
    const float* Blv   = (const float*)d_in[9];
    const float* eps   = (const float*)d_in[10];
    const float* Wc    = (const float*)d_in[11];
    const float* We    = (const float*)d_in[12];
    const float* nbias = (const float*)d_in[13];
    const float* ntau  = (const float*)d_in[14];
    const float* aw    = (const float*)d_in[15];
    const float* ab    = (const float*)d_in[16];
    const float* fsc   = (const float*)d_in[17];
    const float* fsh   = (const float*)d_in[18];
    const float* ctau  = (const float*)d_in[19];

    float* out    = (float*)d_out;
    float* o_muv  = out + 0*(size_t)NTOT;
    float* o_mufl = out + 1*(size_t)NTOT;
    float* o_mul  = out + 2*(size_t)NTOT;
    float* o_lvl  = out + 3*(size_t)NTOT;
    float* o_samp = out + 4*(size_t)NTOT;
    float* o_cact = out + 5*(size_t)NTOT;
    float* o_mcal = out + 6*(size_t)NTOT;
    float* o_rec  = out + 7*(size_t)NTOT;
    float* o_sens = out + 8*(size_t)NTOT;

    // workspace: Xt1 (16384x640 bf16), Xt2 (same), Wlat (640x640), Wrec (384x640)
    char*  wsb  = (char*)d_ws;
    short* Xt1  = (short*)(wsb);
    short* Xt2  = (short*)(wsb + 20971520);
    short* Wlat = (short*)(wsb + 41943040);
    short* Wrec = (short*)(wsb + 41943040 + 819200);

    hipLaunchKernelGGL(k_prepW, dim3(1024), dim3(256), 0, stream,
                       Amu, Bmu, Alv, Blv, Wc, We, Wlat, Wrec);
    hipLaunchKernelGGL(k_stage1, dim3(TT/256), dim3(256), 0, stream,
                       odor, Wenc, benc, mask, raw, o_sens, Xt1, Xt2);
    hipLaunchKernelGGL(k_gemm1, dim3(TT/128, 5), dim3(256), 0, stream,
                       Wlat, Xt1, eps, o_mul, o_lvl, o_samp, Xt2);
    hipLaunchKernelGGL(k_gemm2, dim3(TT/128, 3), dim3(256), 0, stream,
                       Wrec, Xt2, o_samp, o_sens, nbias, ntau, aw, ab,
                       o_rec, o_muv, o_cact);
    hipLaunchKernelGGL(k_scan, dim3(NN), dim3(256), 0, stream,
                       o_cact, ffull, ctau, fsc, fsh, o_mufl, o_mcal);
}

// Round 4
// 447.964 us; speedup vs baseline: 3.4283x; 1.2960x over previous
//
#include <hip/hip_runtime.h>
#include <math.h>

// WormNetCalcium, MFMA pipeline v3.1 (fix: k_stage1 blds/mlds strided fill).
// Factorization: mu/lv = (A @ raw)[:, t>>4] + B @ S  -> Cf(640x1024) + main GEMM K=320.
// All MFMA operands live in tiled layouts: tile = 128 rows x 32 k, 8KB contiguous,
// so GEMM staging is linear global_load_lds and all producers write coalesced.
// Outputs: 0 muv 1 mufl 2 mulat 3 lvlat 4 sample 5 cact 6 mucal 7 rec 8 sens

#define NN    300
#define WINSZ 1024
#define TT    16384
#define DTC   0.2f
#define NTOT  (NN * TT)

typedef short  short8  __attribute__((ext_vector_type(8)));
typedef short  short4v __attribute__((ext_vector_type(4)));
typedef float  f32x4   __attribute__((ext_vector_type(4)));

#define GLOAD16(gp, lp) __builtin_amdgcn_global_load_lds( \
    (const __attribute__((address_space(1))) void*)(gp),  \
    (__attribute__((address_space(3))) void*)(lp), 16, 0, 0)

__device__ inline short bf16rne(float f) {
    unsigned u = __float_as_uint(f);
    u += 0x7fffu + ((u >> 16) & 1u);
    return (short)(u >> 16);
}

// ---------- prepW: build tiled bf16 operand buffers ----------
__global__ __launch_bounds__(256) void k_prepW(
    const float* __restrict__ Amu, const float* __restrict__ Bmu,
    const float* __restrict__ Alv, const float* __restrict__ Blv,
    const float* __restrict__ Wc,  const float* __restrict__ We,
    const float* __restrict__ raw,
    short* __restrict__ WlatS, short* __restrict__ WF,
    short* __restrict__ Wrec,  short* __restrict__ rawT)
{
    int b = blockIdx.x, tid = threadIdx.x;
    #pragma unroll
    for (int pass = 0; pass < 2; ++pass) {
        int idx = pass*256 + tid;          // int4 index in tile [0,512)
        int rl = idx >> 2, k8 = idx & 3;   // row-in-tile, k-chunk
        short8 v;
        short* dst;
        if (b < 50) {
            int mt = b/10, kt = b%10;
            int row = mt*128 + rl, k0 = kt*32 + k8*8;
            dst = WlatS + ((size_t)(mt*10 + kt))*4096 + idx*8;
            #pragma unroll
            for (int j = 0; j < 8; ++j) {
                int k = k0 + j; float x = 0.f;
                if (row < 600 && k < 300) {
                    const float* B = (row & 1) ? Blv : Bmu;
                    x = B[(row>>1)*300 + k];
                }
                v[j] = bf16rne(x);
            }
        } else if (b < 100) {
            int bb = b-50, mt = bb/10, kt = bb%10;
            int row = mt*128 + rl, k0 = kt*32 + k8*8;
            dst = WF + ((size_t)(mt*10 + kt))*4096 + idx*8;
            #pragma unroll
            for (int j = 0; j < 8; ++j) {
                int k = k0 + j; float x = 0.f;
                if (row < 600 && k < 300) {
                    const float* A = (row & 1) ? Alv : Amu;
                    x = A[(row>>1)*300 + k];
                }
                v[j] = bf16rne(x);
            }
        } else if (b < 160) {
            int bb = b-100, mt = bb/20, kt = bb%20;
            int m = mt*128 + rl, k0 = kt*32 + k8*8;
            dst = Wrec + ((size_t)(mt*20 + kt))*4096 + idx*8;
            #pragma unroll
            for (int j = 0; j < 8; ++j) {
                int k = k0 + j; float x = 0.f;
                if (m < 300) {
                    if (k < 300)                  x = Wc[m*300 + k];
                    else if (k >= 304 && k < 604) x = We[m*300 + (k-304)];
                }
                v[j] = bf16rne(x);
            }
        } else {
            int bb = b-160, tt = bb/10, kt = bb%10;
            int t = tt*128 + rl, k0 = kt*32 + k8*8;
            dst = rawT + ((size_t)(tt*10 + kt))*4096 + idx*8;
            #pragma unroll
            for (int j = 0; j < 8; ++j) {
                int k = k0 + j; float x = 0.f;
                if (k < 300) x = raw[k*WINSZ + t];
                v[j] = bf16rne(x);
            }
        }
        *(short8*)dst = v;
    }
}

// ---------- k_sens: sensory_input (N,T) fp32, coalesced in t ----------
__global__ __launch_bounds__(256) void k_sens(
    const float* __restrict__ odor, const float* __restrict__ Wenc,
    const float* __restrict__ benc, const float* __restrict__ mask,
    float* __restrict__ S)
{
    int t  = blockIdx.x*256 + threadIdx.x;
    int n0 = blockIdx.y*15;
    float o[16];
    const float4* op = reinterpret_cast<const float4*>(odor + (size_t)t*16);
    #pragma unroll
    for (int i = 0; i < 4; ++i) {
        float4 w = op[i];
        o[4*i+0]=w.x; o[4*i+1]=w.y; o[4*i+2]=w.z; o[4*i+3]=w.w;
    }
    #pragma unroll
    for (int i = 0; i < 15; ++i) {
        int n = n0 + i;
        float e = benc[n];
        #pragma unroll
        for (int k = 0; k < 16; ++k) e = fmaf(o[k], Wenc[n*16+k], e);
        S[(size_t)n*TT + t] = e * mask[n];
    }
}

// ---------- k_stage1: Xt1 tiled bf16 = S^T (t rows, k=n cols), K=320 ----------
__global__ __launch_bounds__(256) void k_stage1(
    const float* __restrict__ odor, const float* __restrict__ Wenc,
    const float* __restrict__ benc, const float* __restrict__ mask,
    short* __restrict__ Xt1)
{
    __shared__ float olds[128*16];
    __shared__ float wlds[300*16];
    __shared__ float blds[304];
    __shared__ float mlds[304];
    int tid = threadIdx.x;
    int t0  = blockIdx.x * 128;
    #pragma unroll
    for (int p = 0; p < 2; ++p) {
        int li = p*256 + tid;
        *(float4*)(olds + li*4) = *(const float4*)(odor + (size_t)t0*16 + li*4);
    }
    for (int p = 0; p < 5; ++p) {
        int li = p*256 + tid;
        if (li < 1200) *(float4*)(wlds + li*4) = *(const float4*)(Wenc + li*4);
    }
    for (int li = tid; li < 300; li += 256) {   // FIX: strided (tid max 255)
        blds[li] = benc[li];
        mlds[li] = mask[li];
    }
    __syncthreads();

    short* base = Xt1 + (size_t)blockIdx.x * (10*4096);
    for (int pass = 0; pass < 20; ++pass) {
        int gi = pass*256 + tid;             // over 10 kt * 512 int4
        int kt = gi >> 9, rr = gi & 511;
        int t_l = rr >> 2, k8 = rr & 3;
        const float4* od = (const float4*)(olds + t_l*16);
        float4 o0 = od[0], o1 = od[1], o2 = od[2], o3 = od[3];
        int n0 = kt*32 + k8*8;
        short8 v;
        #pragma unroll
        for (int j = 0; j < 8; ++j) {
            int n = n0 + j; float s = 0.f;
            if (n < 300) {
                const float4* wr4 = (const float4*)(wlds + n*16);
                float4 w0 = wr4[0], w1 = wr4[1], w2 = wr4[2], w3 = wr4[3];
                float e = blds[n];
                e = fmaf(o0.x,w0.x,e); e = fmaf(o0.y,w0.y,e); e = fmaf(o0.z,w0.z,e); e = fmaf(o0.w,w0.w,e);
                e = fmaf(o1.x,w1.x,e); e = fmaf(o1.y,w1.y,e); e = fmaf(o1.z,w1.z,e); e = fmaf(o1.w,w1.w,e);
                e = fmaf(o2.x,w2.x,e); e = fmaf(o2.y,w2.y,e); e = fmaf(o2.z,w2.z,e); e = fmaf(o2.w,w2.w,e);
                e = fmaf(o3.x,w3.x,e); e = fmaf(o3.y,w3.y,e); e = fmaf(o3.z,w3.z,e); e = fmaf(o3.w,w3.w,e);
                s = e * mlds[n];
            }
            v[j] = bf16rne(s);
        }
        *(short8*)(base + (size_t)kt*4096 + (size_t)rr*8) = v;
    }
}

// ---------- shared MFMA K-loop (tiled operands, global_load_lds) ----------
__device__ inline void mfma_kloop(const short* __restrict__ ga0,
                                  const short* __restrict__ gb0,
                                  int nkt, short* Asm, short* Bsm,
                                  f32x4 (*acc)[4])
{
    int tid  = threadIdx.x;
    int lane = tid & 63, wv = tid >> 6;
    int wr = wv >> 1, wc = wv & 1;
    for (int kt = 0; kt < nkt; ++kt) {
        __syncthreads();
        const short* ga = ga0 + (size_t)kt*4096;
        const short* gb = gb0 + (size_t)kt*4096;
        short* la = Asm + wv*512;
        short* lb = Bsm + wv*512;
        GLOAD16(ga + tid*8,        la);
        GLOAD16(ga + 2048 + tid*8, la + 2048);
        GLOAD16(gb + tid*8,        lb);
        GLOAD16(gb + 2048 + tid*8, lb + 2048);
        __syncthreads();
        short8 a[4], b[4];
        #pragma unroll
        for (int mi = 0; mi < 4; ++mi)
            a[mi] = *(const short8*)(Asm + (wr*64 + mi*16 + (lane&15))*32 + ((lane>>4)<<3));
        #pragma unroll
        for (int ni = 0; ni < 4; ++ni)
            b[ni] = *(const short8*)(Bsm + (wc*64 + ni*16 + (lane&15))*32 + ((lane>>4)<<3));
        #pragma unroll
        for (int mi = 0; mi < 4; ++mi)
            #pragma unroll
            for (int ni = 0; ni < 4; ++ni)
                acc[mi][ni] = __builtin_amdgcn_mfma_f32_16x16x32_bf16(a[mi], b[ni], acc[mi][ni], 0, 0, 0);
    }
}

// ---------- gemmF: Cf(640x1024) = WF @ rawT ----------
__global__ __launch_bounds__(256) void k_gemmF(
    const short* __restrict__ WF, const short* __restrict__ rawT,
    float* __restrict__ Cf)
{
    __shared__ short Asm[4096];
    __shared__ short Bsm[4096];
    int lane = threadIdx.x & 63, wv = threadIdx.x >> 6;
    int wr = wv >> 1, wc = wv & 1;
    int n0 = blockIdx.x*128, m0 = blockIdx.y*128;
    f32x4 acc[4][4];
    #pragma unroll
    for (int a = 0; a < 4; ++a)
        #pragma unroll
        for (int b = 0; b < 4; ++b) acc[a][b] = (f32x4)(0.f);
    mfma_kloop(WF + (size_t)blockIdx.y*10*4096, rawT + (size_t)blockIdx.x*10*4096,
               10, Asm, Bsm, acc);
    #pragma unroll
    for (int mi = 0; mi < 4; ++mi) {
        int row = m0 + wr*64 + mi*16 + ((lane>>4)<<2);
        #pragma unroll
        for (int ni = 0; ni < 4; ++ni) {
            int gt = n0 + wc*64 + ni*16 + (lane&15);
            f32x4 v = acc[mi][ni];
            #pragma unroll
            for (int r = 0; r < 4; ++r)
                Cf[(size_t)(row+r)*WINSZ + gt] = v[r];
        }
    }
}

// ---------- gemm1: mu/lv = WlatS @ S^T + Cf[:,t>>4]; sample ----------
__global__ __launch_bounds__(256) void k_gemm1(
    const short* __restrict__ WlatS, const short* __restrict__ Xt1,
    const float* __restrict__ Cf, const float* __restrict__ eps,
    float* __restrict__ mu_lat, float* __restrict__ lv_lat,
    float* __restrict__ sample)
{
    __shared__ short Asm[4096];
    __shared__ short Bsm[4096];
    int lane = threadIdx.x & 63, wv = threadIdx.x >> 6;
    int wr = wv >> 1, wc = wv & 1;
    int n0 = blockIdx.x*128, m0 = blockIdx.y*128;
    f32x4 acc[4][4];
    #pragma unroll
    for (int a = 0; a < 4; ++a)
        #pragma unroll
        for (int b = 0; b < 4; ++b) acc[a][b] = (f32x4)(0.f);
    mfma_kloop(WlatS + (size_t)blockIdx.y*10*4096, Xt1 + (size_t)blockIdx.x*10*4096,
               10, Asm, Bsm, acc);
    #pragma unroll
    for (int mi = 0; mi < 4; ++mi) {
        int gmB = m0 + wr*64 + mi*16 + ((lane>>4)<<2);  // even
        if (gmB >= 600) continue;
        int i0 = gmB >> 1;
        #pragma unroll
        for (int ni = 0; ni < 4; ++ni) {
            int gt = n0 + wc*64 + ni*16 + (lane&15);
            int tw = gt >> 4;
            f32x4 v = acc[mi][ni];
            {
                size_t idx = (size_t)i0*TT + gt;
                float mu = v[0] + Cf[(size_t)gmB*WINSZ + tw];
                float lv = v[1] + Cf[(size_t)(gmB+1)*WINSZ + tw];
                mu_lat[idx] = mu; lv_lat[idx] = lv;
                sample[idx] = fmaf(expf(0.5f*lv), eps[idx], mu);
            }
            if (i0 + 1 < NN) {
                size_t idx = (size_t)(i0+1)*TT + gt;
                float mu = v[2] + Cf[(size_t)(gmB+2)*WINSZ + tw];
                float lv = v[3] + Cf[(size_t)(gmB+3)*WINSZ + tw];
                mu_lat[idx] = mu; lv_lat[idx] = lv;
                sample[idx] = fmaf(expf(0.5f*lv), eps[idx], mu);
            }
        }
    }
}

// ---------- buildX2: Xt2 tiled bf16 = [relu(s); s]^T via LDS transpose ----------
__global__ __launch_bounds__(256) void k_buildX2(
    const float* __restrict__ sample, short* __restrict__ Xt2)
{
    __shared__ short slds[300*68];
    int tid = threadIdx.x;
    int t0  = blockIdx.x * 64;
    for (int p = 0; p < 19; ++p) {
        int li = p*256 + tid;
        if (li < 4800) {
            int n = li >> 4, c = li & 15;
            float4 v = *(const float4*)(sample + (size_t)n*TT + t0 + c*4);
            short4v s;
            s[0]=bf16rne(v.x); s[1]=bf16rne(v.y); s[2]=bf16rne(v.z); s[3]=bf16rne(v.w);
            *(short4v*)(slds + n*68 + c*4) = s;
        }
    }
    __syncthreads();
    int ttile = t0 >> 7, trow = t0 & 127;
    short* base = Xt2 + (size_t)ttile*(20*4096);
    for (int p = 0; p < 20; ++p) {
        int gi = p*256 + tid;                 // 20 kt * 256 int4(half-tile)
        int kt = gi >> 8, rr = gi & 255;
        int t_l = rr >> 2, k8 = rr & 3;
        int k0 = kt*32 + k8*8;
        short8 v;
        #pragma unroll
        for (int j = 0; j < 8; ++j) {
            int k = k0 + j; short x = 0;
            if (k < 300) {
                short s = slds[k*68 + t_l];
                x = (s & (short)0x8000) ? (short)0 : s;   // relu in bf16
            } else if (k >= 304 && k < 604) {
                x = slds[(k-304)*68 + t_l];
            }
            v[j] = x;
        }
        *(short8*)(base + (size_t)kt*4096 + (trow + t_l)*32 + k8*8) = v;
    }
}

// ---------- gemm2: rec = Wrec @ X2; muv, cact ----------
__global__ __launch_bounds__(256) void k_gemm2(
    const short* __restrict__ Wrec, const short* __restrict__ Xt2,
    const float* __restrict__ sample, const float* __restrict__ S,
    const float* __restrict__ bias, const float* __restrict__ tau,
    const float* __restrict__ aw, const float* __restrict__ ab,
    float* __restrict__ rec, float* __restrict__ muv, float* __restrict__ cact)
{
    __shared__ short Asm[4096];
    __shared__ short Bsm[4096];
    int lane = threadIdx.x & 63, wv = threadIdx.x >> 6;
    int wr = wv >> 1, wc = wv & 1;
    int n0 = blockIdx.x*128, m0 = blockIdx.y*128;
    f32x4 acc[4][4];
    #pragma unroll
    for (int a = 0; a < 4; ++a)
        #pragma unroll
        for (int b = 0; b < 4; ++b) acc[a][b] = (f32x4)(0.f);
    mfma_kloop(Wrec + (size_t)blockIdx.y*20*4096, Xt2 + (size_t)blockIdx.x*20*4096,
               20, Asm, Bsm, acc);
    #pragma unroll
    for (int mi = 0; mi < 4; ++mi) {
        int gmB = m0 + wr*64 + mi*16 + ((lane>>4)<<2);
        if (gmB >= NN) continue;
        #pragma unroll
        for (int ni = 0; ni < 4; ++ni) {
            int gt = n0 + wc*64 + ni*16 + (lane&15);
            f32x4 v = acc[mi][ni];
            #pragma unroll
            for (int r = 0; r < 4; ++r) {
                int n = gmB + r;
                if (n < NN) {
                    size_t idx = (size_t)n*TT + gt;
                    float rv = v[r];
                    float s  = sample[idx];
                    float sv = S[idx];
                    float av = DTC / fmaxf(tau[n], DTC);
                    rec[idx] = rv;
                    muv[idx] = s + av * (-s + rv + sv + bias[n]);
                    float xx = fmaf(aw[n], s, ab[n]);
                    cact[idx] = fmaxf(xx, 0.f) + log1pf(expf(-fabsf(xx)));
                }
            }
        }
    }
}

// ---------- scan: c[t]=decay*c[t-1]+x[t], c[0]=init+x[0]; 512 thr, par. carry ----
__global__ __launch_bounds__(512) void k_scan(
    const float* __restrict__ cact, const float* __restrict__ ffull,
    const float* __restrict__ ctau, const float* __restrict__ fscale,
    const float* __restrict__ fshift,
    float* __restrict__ mu_fl, float* __restrict__ mu_cal)
{
    __shared__ float Ax[512];
    __shared__ float Bx[512];
    int n   = blockIdx.x;
    int tid = threadIdx.x;
    float alpha = DTC / fmaxf(ctau[n], DTC);
    float decay = expf(-alpha);
    float d32   = expf(-32.f * alpha);
    float scale = fscale[n], shift = fshift[n];
    float init  = (ffull[(size_t)n*TT] - shift) / scale;

    const float4* x4 = reinterpret_cast<const float4*>(cact + (size_t)n*TT + tid*32);
    float4 xv[8];
    #pragma unroll
    for (int i = 0; i < 8; ++i) xv[i] = x4[i];

    float acc = (tid == 0) ? (init + xv[0].x) : xv[0].x;
    acc = fmaf(decay, acc, xv[0].y);
    acc = fmaf(decay, acc, xv[0].z);
    acc = fmaf(decay, acc, xv[0].w);
    #pragma unroll
    for (int i = 1; i < 8; ++i) {
        acc = fmaf(decay, acc, xv[i].x);
        acc = fmaf(decay, acc, xv[i].y);
        acc = fmaf(decay, acc, xv[i].z);
        acc = fmaf(decay, acc, xv[i].w);
    }
    float A_r = (tid == 0) ? 0.f : d32;
    float B_r = acc;
    Ax[tid] = A_r; Bx[tid] = B_r;
    __syncthreads();
    for (int off = 1; off < 512; off <<= 1) {
        float pa = 0.f, pb = 0.f;
        if (tid >= off) { pa = Ax[tid-off]; pb = Bx[tid-off]; }
        __syncthreads();
        if (tid >= off) {
            B_r = fmaf(A_r, pb, B_r);
            A_r = A_r * pa;
            Ax[tid] = A_r; Bx[tid] = B_r;
        }
        __syncthreads();
    }
    float carry = (tid == 0) ? 0.f : Bx[tid-1];

    float4* ocal = reinterpret_cast<float4*>(mu_cal + (size_t)n*TT + tid*32);
    float4* ofl  = reinterpret_cast<float4*>(mu_fl  + (size_t)n*TT + tid*32);
    float c;
    if (tid == 0) c = init + xv[0].x;
    else          c = fmaf(decay, carry, xv[0].x);
    float4 oc, of;
    oc.x = c; of.x = fmaf(scale, c, shift);
    c = fmaf(decay, c, xv[0].y); oc.y = c; of.y = fmaf(scale, c, shift);
    c = fmaf(decay, c, xv[0].z); oc.z = c; of.z = fmaf(scale, c, shift);
    c = fmaf(decay, c, xv[0].w); oc.w = c; of.w = fmaf(scale, c, shift);
    ocal[0] = oc; ofl[0] = of;
    #pragma unroll
    for (int i = 1; i < 8; ++i) {
        c = fmaf(decay, c, xv[i].x); oc.x = c; of.x = fmaf(scale, c, shift);
        c = fmaf(decay, c, xv[i].y); oc.y = c; of.y = fmaf(scale, c, shift);
        c = fmaf(decay, c, xv[i].z); oc.z = c; of.z = fmaf(scale, c, shift);
        c = fmaf(decay, c, xv[i].w); oc.w = c; of.w = fmaf(scale, c, shift);
        ocal[i] = oc; ofl[i] = of;
    }
}

extern "C" void kernel_launch(void* const* d_in, const int* in_sizes, int n_in,
                              void* d_out, int out_size, void* d_ws, size_t ws_size,
                              hipStream_t stream) {
    const float* raw   = (const float*)d_in[0];
    const float* ffull = (const float*)d_in[1];
    const float* odor  = (const float*)d_in[2];
    const float* mask  = (const float*)d_in[3];
    const float* Wenc  = (const float*)d_in[4];
    const float* benc  = (const float*)d_in[5];
    const float* Amu   = (const float*)d_in[6];
    const float* Bmu   = (const float*)d_in[7];
    const float* Alv   = (const float*)d_in[8];
    const float* Blv   = (const float*)d_in[9];
    const float* eps   = (const float*)d_in[10];
    const float* Wc    = (const float*)d_in[11];
    const float* We    = (const float*)d_in[12];
    const float* nbias = (const float*)d_in[13];
    const float* ntau  = (const float*)d_in[14];
    const float* aw    = (const float*)d_in[15];
    const float* ab    = (const float*)d_in[16];
    const float* fsc   = (const float*)d_in[17];
    const float* fsh   = (const float*)d_in[18];
    const float* ctau  = (const float*)d_in[19];

    float* out    = (float*)d_out;
    float* o_muv  = out + 0*(size_t)NTOT;
    float* o_mufl = out + 1*(size_t)NTOT;
    float* o_mul  = out + 2*(size_t)NTOT;
    float* o_lvl  = out + 3*(size_t)NTOT;
    float* o_samp = out + 4*(size_t)NTOT;
    float* o_cact = out + 5*(size_t)NTOT;
    float* o_mcal = out + 6*(size_t)NTOT;
    float* o_rec  = out + 7*(size_t)NTOT;
    float* o_sens = out + 8*(size_t)NTOT;

    char*  wsb   = (char*)d_ws;
    short* Xt1   = (short*)(wsb);                       // 10,485,760
    short* Xt2   = (short*)(wsb + 10485760);            // 20,971,520
    short* rawT  = (short*)(wsb + 31457280);            //    655,360
    short* WlatS = (short*)(wsb + 32112640);            //    409,600
    short* WF    = (short*)(wsb + 32522240);            //    409,600
    short* Wrec  = (short*)(wsb + 32931840);            //    491,520
    float* Cf    = (float*)(wsb + 33423360);            //  2,621,440

    hipLaunchKernelGGL(k_prepW, dim3(240), dim3(256), 0, stream,
                       Amu, Bmu, Alv, Blv, Wc, We, raw, WlatS, WF, Wrec, rawT);
    hipLaunchKernelGGL(k_sens, dim3(TT/256, 20), dim3(256), 0, stream,
                       odor, Wenc, benc, mask, o_sens);
    hipLaunchKernelGGL(k_stage1, dim3(TT/128), dim3(256), 0, stream,
                       odor, Wenc, benc, mask, Xt1);
    hipLaunchKernelGGL(k_gemmF, dim3(WINSZ/128, 5), dim3(256), 0, stream,
                       WF, rawT, Cf);
    hipLaunchKernelGGL(k_gemm1, dim3(TT/128, 5), dim3(256), 0, stream,
                       WlatS, Xt1, Cf, eps, o_mul, o_lvl, o_samp);
    hipLaunchKernelGGL(k_buildX2, dim3(TT/64), dim3(256), 0, stream,
                       o_samp, Xt2);
    hipLaunchKernelGGL(k_gemm2, dim3(TT/128, 3), dim3(256), 0, stream,
                       Wrec, Xt2, o_samp, o_sens, nbias, ntau, aw, ab,
                       o_rec, o_muv, o_cact);
    hipLaunchKernelGGL(k_scan, dim3(NN), dim3(512), 0, stream,
                       o_cact, ffull, ctau, fsc, fsh, o_mufl, o_mcal);
}